// Round 1
// baseline (124.060 us; speedup 1.0000x reference)
//
#include <hip/hip_runtime.h>

#define NS 25
#define NQ 200
#define FG 16
#define FL 64
#define FTOT 80
#define D 512
#define WAY 5
#define MROWS 2000    // 25*80 support rows
#define MPAD 2080     // padded to 13 tiles of 160
#define NROWS 16000   // 200*80 query rows

typedef unsigned char u8;
typedef __attribute__((ext_vector_type(4))) float floatx4;
typedef __attribute__((ext_vector_type(4))) int intx4;
typedef __attribute__((ext_vector_type(8))) int intx8;

__device__ inline void gload_lds16(const void* g, void* l) {
    __builtin_amdgcn_global_load_lds(
        (const __attribute__((address_space(1))) unsigned int*)g,
        (__attribute__((address_space(3))) unsigned int*)l, 16, 0, 0);
}

// One wave per 512-elem row: L2-normalize, cast fp8 e4m3 (OCP), write concat
// layout. Block 4500: zero Sn pad rows + zero out[] + per-class 1/count.
__global__ void normalize_kernel(const float* __restrict__ sg, const float* __restrict__ sl,
                                 const float* __restrict__ qg, const float* __restrict__ ql,
                                 u8* __restrict__ Sn, u8* __restrict__ Qn,
                                 const int* __restrict__ labels,
                                 float* __restrict__ out, float* __restrict__ rcnt) {
    if (blockIdx.x == 4500) {
        intx4 z = {0, 0, 0, 0};
        intx4* pad = (intx4*)(Sn + (size_t)MROWS * D);   // 80 rows * 512 B = 2560 intx4
        for (int i = threadIdx.x; i < (MPAD - MROWS) * D / 16; i += 256) pad[i] = z;
        for (int i = threadIdx.x; i < NQ * WAY; i += 256) out[i] = 0.f;
        if (threadIdx.x == 0) {
            int counts[WAY] = {0, 0, 0, 0, 0};
            for (int s = 0; s < NS; ++s) counts[labels[s]]++;
            for (int c = 0; c < WAY; ++c) rcnt[c] = 1.0f / (float)(counts[c] ? counts[c] : 1);
        }
        return;
    }
    int wave = (blockIdx.x * blockDim.x + threadIdx.x) >> 6;
    int lane = threadIdx.x & 63;
    const int totalRows = MROWS + NROWS;   // 18000
    if (wave >= totalRows) return;

    const float* src;
    u8* dst;
    if (wave < MROWS) {
        int s = wave / FTOT, f = wave % FTOT;
        src = (f < FG) ? sg + (size_t)(s * FG + f) * D
                       : sl + (size_t)(s * FL + (f - FG)) * D;
        dst = Sn + (size_t)wave * D;
    } else {
        int r = wave - MROWS;
        int q = r / FTOT, f = r % FTOT;
        src = (f < FG) ? qg + (size_t)(q * FG + f) * D
                       : ql + (size_t)(q * FL + (f - FG)) * D;
        dst = Qn + (size_t)r * D;
    }

    // lane holds 8 contiguous elements [8*lane .. 8*lane+8)
    float4 v0 = ((const float4*)src)[2 * lane];
    float4 v1 = ((const float4*)src)[2 * lane + 1];
    float ss = v0.x*v0.x + v0.y*v0.y + v0.z*v0.z + v0.w*v0.w
             + v1.x*v1.x + v1.y*v1.y + v1.z*v1.z + v1.w*v1.w;
    #pragma unroll
    for (int off = 32; off > 0; off >>= 1) ss += __shfl_xor(ss, off, 64);
    float scale = 1.0f / fmaxf(sqrtf(ss), 1e-12f);

    int w0 = __builtin_amdgcn_cvt_pk_fp8_f32(v0.x * scale, v0.y * scale, 0, false);
    w0     = __builtin_amdgcn_cvt_pk_fp8_f32(v0.z * scale, v0.w * scale, w0, true);
    int w1 = __builtin_amdgcn_cvt_pk_fp8_f32(v1.x * scale, v1.y * scale, 0, false);
    w1     = __builtin_amdgcn_cvt_pk_fp8_f32(v1.z * scale, v1.w * scale, w1, true);
    ((int2*)dst)[lane] = make_int2(w0, w1);
}

// 160x160-tile fp8 NT GEMM aligned to 80-row groups; BK=128, XOR-swizzled LDS.
// 4 waves 2x2, each owns one 80x80 (s,q) block = 5x5 MFMA tiles.
// MX-scaled mfma_scale_f32_16x16x128_f8f6f4 with unit (e8m0=127) scales:
// 2.27x the non-scaled fp8 rate, numerically identical. One MFMA per BK chunk
// per tile (was 4x 16x16x32).
// Epilogue: sum (1-sim)^2 -> fused class-mean logits via one atomic per wave.
__global__ __launch_bounds__(256, 3) void gemm_kernel(const u8* __restrict__ Sn,
                                                      const u8* __restrict__ Qn,
                                                      const int* __restrict__ labels,
                                                      const float* __restrict__ rcnt,
                                                      float* __restrict__ out) {
    __shared__ u8 As[160][128];   // fp8, BK=128; 16B chunk c holds global chunk c^((r>>1)&7)
    __shared__ u8 Bs[160][128];

    const int bx = blockIdx.x;          // 0..99  (query groups, 2 per block)
    const int by = blockIdx.y;          // 0..12  (support groups, 2 per block)
    const int tid = threadIdx.x;
    const int lane = tid & 63;
    const int w = tid >> 6;
    const int lm = lane & 15;
    const int lq = lane >> 4;
    const int wr = w >> 1;              // which 80-row half
    const int wc = w & 1;               // which 80-col half

    floatx4 acc[5][5];
    #pragma unroll
    for (int i = 0; i < 5; ++i)
        #pragma unroll
        for (int j = 0; j < 5; ++j) acc[i][j] = (floatx4){0.f, 0.f, 0.f, 0.f};

    const u8* Sbase = Sn + (size_t)by * 160 * D;
    const u8* Qbase = Qn + (size_t)bx * 160 * D;

    // staging: waves 0,1 -> A; waves 2,3 -> B. 20 slabs of 8 rows (1 KB each).
    const u8* gsrc = (w < 2) ? Sbase : Qbase;
    u8* ldst = (w < 2) ? (u8*)As : (u8*)Bs;
    const int sl0 = (w & 1) * 10;
    const int grow = lane >> 3;         // row within 8-row slab
    const int gc = lane & 7;            // 16B slot-chunk within 128B row

    // fragment read: lane needs global k-chunks 2lq,2lq+1 of this BK window,
    // stored at slot chunks (2lq)^s,(2lq+1)^s where s=(r>>1)&7.
    #pragma unroll 1
    for (int kc = 0; kc < 4; ++kc) {
        const int k0 = kc * 128;
        __syncthreads();                // prev chunk's readers done
        #pragma unroll
        for (int t = 0; t < 10; ++t) {
            const int sl = sl0 + t;
            const int r = sl * 8 + grow;
            const int cp = gc ^ ((r >> 1) & 7);
            gload_lds16(gsrc + (size_t)r * D + k0 + cp * 16, ldst + sl * 1024);
        }
        __syncthreads();                // drains vmcnt (global_load_lds) too

        intx8 bfr[5];
        #pragma unroll
        for (int j = 0; j < 5; ++j) {
            const int r = wc * 80 + j * 16 + lm;
            const int s = (r >> 1) & 7;
            intx4 lo = *(const intx4*)(&Bs[r][((2 * lq + 0) ^ s) * 16]);
            intx4 hi = *(const intx4*)(&Bs[r][((2 * lq + 1) ^ s) * 16]);
            bfr[j][0] = lo[0]; bfr[j][1] = lo[1]; bfr[j][2] = lo[2]; bfr[j][3] = lo[3];
            bfr[j][4] = hi[0]; bfr[j][5] = hi[1]; bfr[j][6] = hi[2]; bfr[j][7] = hi[3];
        }
        #pragma unroll
        for (int i = 0; i < 5; ++i) {
            const int r = wr * 80 + i * 16 + lm;
            const int s = (r >> 1) & 7;
            intx4 lo = *(const intx4*)(&As[r][((2 * lq + 0) ^ s) * 16]);
            intx4 hi = *(const intx4*)(&As[r][((2 * lq + 1) ^ s) * 16]);
            intx8 afr;
            afr[0] = lo[0]; afr[1] = lo[1]; afr[2] = lo[2]; afr[3] = lo[3];
            afr[4] = hi[0]; afr[5] = hi[1]; afr[6] = hi[2]; afr[7] = hi[3];
            #pragma unroll
            for (int j = 0; j < 5; ++j)
                acc[i][j] = __builtin_amdgcn_mfma_scale_f32_16x16x128_f8f6f4(
                    afr, bfr[j], acc[i][j], 0, 0,
                    0, 0x7F7F7F7F, 0, 0x7F7F7F7F);
        }
    }

    // Epilogue: sum (1-sim)^2 over the wave's 80x80 block, fuse class-mean.
    float local = 0.f;
    #pragma unroll
    for (int i = 0; i < 5; ++i)
        #pragma unroll
        for (int j = 0; j < 5; ++j)
            #pragma unroll
            for (int r = 0; r < 4; ++r) {
                const float d = 1.0f - acc[i][j][r];
                local = fmaf(d, d, local);
            }
    #pragma unroll
    for (int off = 32; off > 0; off >>= 1) local += __shfl_down(local, off, 64);

    const int sIdx = by * 2 + wr;       // 25 = pad group, dropped
    const int qIdx = bx * 2 + wc;
    if (lane == 0 && sIdx < NS) {
        const int c = labels[sIdx];
        atomicAdd(&out[qIdx * WAY + c], -2.0f * local * rcnt[c]);
    }
}

extern "C" void kernel_launch(void* const* d_in, const int* in_sizes, int n_in,
                              void* d_out, int out_size, void* d_ws, size_t ws_size,
                              hipStream_t stream) {
    const float* sg = (const float*)d_in[0];
    const float* sl = (const float*)d_in[1];
    const int* labels = (const int*)d_in[2];
    const float* qg = (const float*)d_in[3];
    const float* ql = (const float*)d_in[4];
    float* out = (float*)d_out;

    u8* Sn = (u8*)d_ws;                          // 2080*512 fp8 (padded)
    u8* Qn = Sn + (size_t)MPAD * D;              // 16000*512 fp8
    float* rcnt = (float*)(Qn + (size_t)NROWS * D);

    normalize_kernel<<<4501, 256, 0, stream>>>(sg, sl, qg, ql, Sn, Qn, labels, out, rcnt);
    dim3 g2(100, 13);
    gemm_kernel<<<g2, 256, 0, stream>>>(Sn, Qn, labels, rcnt, out);
}

// Round 2
// 121.605 us; speedup vs baseline: 1.0202x; 1.0202x over previous
//
#include <hip/hip_runtime.h>

#define NS 25
#define NQ 200
#define FG 16
#define FL 64
#define FTOT 80
#define D 512
#define WAY 5
#define MROWS 2000    // 25*80 support rows
#define MPAD 2080     // padded to 13 tiles of 160
#define NROWS 16000   // 200*80 query rows

typedef unsigned char u8;
typedef __attribute__((ext_vector_type(4))) float floatx4;
typedef __attribute__((ext_vector_type(4))) int intx4;
typedef __attribute__((ext_vector_type(8))) int intx8;

__device__ inline void gload_lds16(const void* g, void* l) {
    __builtin_amdgcn_global_load_lds(
        (const __attribute__((address_space(1))) unsigned int*)g,
        (__attribute__((address_space(3))) unsigned int*)l, 16, 0, 0);
}

// One wave per 512-elem row: L2-normalize, cast fp8 e4m3 (OCP), write concat
// layout. Block 4500: zero Sn pad rows + zero out[] + per-class 1/count.
__global__ void normalize_kernel(const float* __restrict__ sg, const float* __restrict__ sl,
                                 const float* __restrict__ qg, const float* __restrict__ ql,
                                 u8* __restrict__ Sn, u8* __restrict__ Qn,
                                 const int* __restrict__ labels,
                                 float* __restrict__ out, float* __restrict__ rcnt) {
    if (blockIdx.x == 4500) {
        intx4 z = {0, 0, 0, 0};
        intx4* pad = (intx4*)(Sn + (size_t)MROWS * D);   // 80 rows * 512 B = 2560 intx4
        for (int i = threadIdx.x; i < (MPAD - MROWS) * D / 16; i += 256) pad[i] = z;
        for (int i = threadIdx.x; i < NQ * WAY; i += 256) out[i] = 0.f;
        if (threadIdx.x == 0) {
            int counts[WAY] = {0, 0, 0, 0, 0};
            for (int s = 0; s < NS; ++s) counts[labels[s]]++;
            for (int c = 0; c < WAY; ++c) rcnt[c] = 1.0f / (float)(counts[c] ? counts[c] : 1);
        }
        return;
    }
    int wave = (blockIdx.x * blockDim.x + threadIdx.x) >> 6;
    int lane = threadIdx.x & 63;
    const int totalRows = MROWS + NROWS;   // 18000
    if (wave >= totalRows) return;

    const float* src;
    u8* dst;
    if (wave < MROWS) {
        int s = wave / FTOT, f = wave % FTOT;
        src = (f < FG) ? sg + (size_t)(s * FG + f) * D
                       : sl + (size_t)(s * FL + (f - FG)) * D;
        dst = Sn + (size_t)wave * D;
    } else {
        int r = wave - MROWS;
        int q = r / FTOT, f = r % FTOT;
        src = (f < FG) ? qg + (size_t)(q * FG + f) * D
                       : ql + (size_t)(q * FL + (f - FG)) * D;
        dst = Qn + (size_t)r * D;
    }

    // lane holds 8 contiguous elements [8*lane .. 8*lane+8)
    float4 v0 = ((const float4*)src)[2 * lane];
    float4 v1 = ((const float4*)src)[2 * lane + 1];
    float ss = v0.x*v0.x + v0.y*v0.y + v0.z*v0.z + v0.w*v0.w
             + v1.x*v1.x + v1.y*v1.y + v1.z*v1.z + v1.w*v1.w;
    #pragma unroll
    for (int off = 32; off > 0; off >>= 1) ss += __shfl_xor(ss, off, 64);
    float scale = 1.0f / fmaxf(sqrtf(ss), 1e-12f);

    int w0 = __builtin_amdgcn_cvt_pk_fp8_f32(v0.x * scale, v0.y * scale, 0, false);
    w0     = __builtin_amdgcn_cvt_pk_fp8_f32(v0.z * scale, v0.w * scale, w0, true);
    int w1 = __builtin_amdgcn_cvt_pk_fp8_f32(v1.x * scale, v1.y * scale, 0, false);
    w1     = __builtin_amdgcn_cvt_pk_fp8_f32(v1.z * scale, v1.w * scale, w1, true);
    ((int2*)dst)[lane] = make_int2(w0, w1);
}

// 160x160-tile fp8 NT GEMM, BK=128, 4 K-chunks.
//  - A (Sn, 1 MB, L2-resident) read DIRECTLY global->reg per chunk (no LDS).
//  - B (Qn) double-buffered in LDS (2x20KB), XOR-swizzled, prefetched one
//    chunk ahead via global_load_lds BEFORE the MFMA cluster (T3 2-phase):
//    the vmcnt(0) drain at the barrier lands after ~900 cyc of MFMA.
//  - MX-scaled mfma_scale_f32_16x16x128_f8f6f4 with unit (e8m0=127) scales:
//    bit-identical to non-scaled fp8, 2.27x the rate, 1 MFMA per chunk/tile.
//  - launch_bounds(256,2): 256-VGPR cap (est. ~210 live), no spill;
//    2 blocks/CU, in-block prefetch supplies the overlap.
// Epilogue: sum (1-sim)^2 -> fused class-mean logits via one atomic per wave.
__global__ __launch_bounds__(256, 2) void gemm_kernel(const u8* __restrict__ Sn,
                                                      const u8* __restrict__ Qn,
                                                      const int* __restrict__ labels,
                                                      const float* __restrict__ rcnt,
                                                      float* __restrict__ out) {
    __shared__ __align__(16) u8 Bs[2][160][128];  // 16B chunk c holds global chunk c^((r>>1)&7)

    const int bx = blockIdx.x;          // 0..99  (query groups, 2 per block)
    const int by = blockIdx.y;          // 0..12  (support groups, 2 per block)
    const int tid = threadIdx.x;
    const int lane = tid & 63;
    const int w = tid >> 6;
    const int lm = lane & 15;
    const int lq = lane >> 4;
    const int wr = w >> 1;              // which 80-row half (support)
    const int wc = w & 1;               // which 80-col half (query)

    floatx4 acc[5][5];
    #pragma unroll
    for (int i = 0; i < 5; ++i)
        #pragma unroll
        for (int j = 0; j < 5; ++j) acc[i][j] = (floatx4){0.f, 0.f, 0.f, 0.f};

    // Per-lane A base: row = by*160 + wr*80 + i*16 + lm, k-offset lq*32.
    const u8* Abase = Sn + (size_t)(by * 160 + wr * 80 + lm) * D + lq * 32;
    const u8* Qbase = Qn + (size_t)bx * 160 * D;
    u8* BsFlat = &Bs[0][0][0];

    // B staging: each of the 4 waves stages 5 slabs of 8 rows (1 KB each).
    const int grow = lane >> 3;         // row within 8-row slab
    const int gc = lane & 7;            // 16B slot-chunk within 128B row
    const int sl0 = w * 5;

    // ---- prologue: stage B chunk 0 into buf0, load A chunk 0 ----
    #pragma unroll
    for (int t = 0; t < 5; ++t) {
        const int sl = sl0 + t;
        const int r = sl * 8 + grow;
        const int cp = gc ^ ((r >> 1) & 7);
        gload_lds16(Qbase + (size_t)r * D + cp * 16, BsFlat + sl * 1024);
    }
    intx8 afr[5];
    #pragma unroll
    for (int i = 0; i < 5; ++i) {
        intx4 lo = *(const intx4*)(Abase + i * 16 * D);
        intx4 hi = *(const intx4*)(Abase + i * 16 * D + 16);
        afr[i][0] = lo[0]; afr[i][1] = lo[1]; afr[i][2] = lo[2]; afr[i][3] = lo[3];
        afr[i][4] = hi[0]; afr[i][5] = hi[1]; afr[i][6] = hi[2]; afr[i][7] = hi[3];
    }
    __syncthreads();                    // vmcnt drained: buf0 + afr ready

    #pragma unroll
    for (int kc = 0; kc < 4; ++kc) {
        // 1) issue B prefetch for chunk kc+1 into the other buffer (async)
        if (kc < 3) {
            const int k0 = (kc + 1) * 128;
            u8* dstb = BsFlat + ((kc + 1) & 1) * 20480;
            #pragma unroll
            for (int t = 0; t < 5; ++t) {
                const int sl = sl0 + t;
                const int r = sl * 8 + grow;
                const int cp = gc ^ ((r >> 1) & 7);
                gload_lds16(Qbase + (size_t)r * D + k0 + cp * 16, dstb + sl * 1024);
            }
        }
        // 2) read B fragments of current chunk from LDS
        const u8* curb = BsFlat + (kc & 1) * 20480;
        intx8 bfr[5];
        #pragma unroll
        for (int j = 0; j < 5; ++j) {
            const int r = wc * 80 + j * 16 + lm;
            const int s = (r >> 1) & 7;
            intx4 lo = *(const intx4*)(curb + r * 128 + ((2 * lq + 0) ^ s) * 16);
            intx4 hi = *(const intx4*)(curb + r * 128 + ((2 * lq + 1) ^ s) * 16);
            bfr[j][0] = lo[0]; bfr[j][1] = lo[1]; bfr[j][2] = lo[2]; bfr[j][3] = lo[3];
            bfr[j][4] = hi[0]; bfr[j][5] = hi[1]; bfr[j][6] = hi[2]; bfr[j][7] = hi[3];
        }
        // 3) MFMA cluster: prefetch latency hides under this
        #pragma unroll
        for (int i = 0; i < 5; ++i)
            #pragma unroll
            for (int j = 0; j < 5; ++j)
                acc[i][j] = __builtin_amdgcn_mfma_scale_f32_16x16x128_f8f6f4(
                    afr[i], bfr[j], acc[i][j], 0, 0,
                    0, 0x7F7F7F7F, 0, 0x7F7F7F7F);
        // 4) load A fragments for chunk kc+1 (global->reg, L2-hit)
        if (kc < 3) {
            const int k0 = (kc + 1) * 128;
            #pragma unroll
            for (int i = 0; i < 5; ++i) {
                intx4 lo = *(const intx4*)(Abase + i * 16 * D + k0);
                intx4 hi = *(const intx4*)(Abase + i * 16 * D + k0 + 16);
                afr[i][0] = lo[0]; afr[i][1] = lo[1]; afr[i][2] = lo[2]; afr[i][3] = lo[3];
                afr[i][4] = hi[0]; afr[i][5] = hi[1]; afr[i][6] = hi[2]; afr[i][7] = hi[3];
            }
        }
        __syncthreads();                // drains vmcnt: next buf + afr ready;
                                        // also orders readers before overwrite
    }

    // Epilogue: sum (1-sim)^2 over the wave's 80x80 block, fuse class-mean.
    float local = 0.f;
    #pragma unroll
    for (int i = 0; i < 5; ++i)
        #pragma unroll
        for (int j = 0; j < 5; ++j)
            #pragma unroll
            for (int r = 0; r < 4; ++r) {
                const float d = 1.0f - acc[i][j][r];
                local = fmaf(d, d, local);
            }
    #pragma unroll
    for (int off = 32; off > 0; off >>= 1) local += __shfl_down(local, off, 64);

    const int sIdx = by * 2 + wr;       // 25 = pad group, dropped
    const int qIdx = bx * 2 + wc;
    if (lane == 0 && sIdx < NS) {
        const int c = labels[sIdx];
        atomicAdd(&out[qIdx * WAY + c], -2.0f * local * rcnt[c]);
    }
}

extern "C" void kernel_launch(void* const* d_in, const int* in_sizes, int n_in,
                              void* d_out, int out_size, void* d_ws, size_t ws_size,
                              hipStream_t stream) {
    const float* sg = (const float*)d_in[0];
    const float* sl = (const float*)d_in[1];
    const int* labels = (const int*)d_in[2];
    const float* qg = (const float*)d_in[3];
    const float* ql = (const float*)d_in[4];
    float* out = (float*)d_out;

    u8* Sn = (u8*)d_ws;                          // 2080*512 fp8 (padded)
    u8* Qn = Sn + (size_t)MPAD * D;              // 16000*512 fp8
    float* rcnt = (float*)(Qn + (size_t)NROWS * D);

    normalize_kernel<<<4501, 256, 0, stream>>>(sg, sl, qg, ql, Sn, Qn, labels, out, rcnt);
    dim3 g2(100, 13);
    gemm_kernel<<<g2, 256, 0, stream>>>(Sn, Qn, labels, rcnt, out);
}